// Round 9
// baseline (117.138 us; speedup 1.0000x reference)
//
#include <hip/hip_runtime.h>

// out[b,i,j,d] = sum_{k<c} A[b,i,k,d] * B[b,k,j,d]   for i,j < c, else 0
// A: (256,64,64,32) f32, strides: b:131072, i:2048, k:32, d:1
// B: (256,64,64,32) f32, strides: b:131072, k:2048, j:32, d:1
//
// v9: v8's XCD-bucketed longest-first schedule (FETCH 52MB, L2 reuse solved)
// + K4 phase-split body: batch 4 k-iters' loads (48 scalar loads in flight)
// BEFORE the 128-FMA group, so one ~250cyc L2-hit stall is amortized over
// 4 iterations instead of paid per-iteration.
// Evidence: v8 VGPR=44 proves compiler emitted load->wait->FMA per k; with
// VALUBusy 15% / HBM 5% / occupancy 29%, exposed per-iter latency is the
// only remaining term. launch_bounds(512,4) caps VGPR at 128 (2 blocks/CU).

#define BATCH 256
#define NN 64
#define ND 32
#define BSTRIDE (NN * NN * ND)   // 131072
#define RSTRIDE (NN * ND)        // 2048
#define ICHUNK 8
#define NITEMS (BATCH * (NN / ICHUNK))  // 2048, item w = b*8 + ic

// ---------------- prologue: per-XCD-bucket counting sort (v8, unchanged) ----
__global__ __launch_bounds__(512) void mp_prologue(
    const int* __restrict__ counts, int* __restrict__ items)
{
    __shared__ int cLds[BATCH];
    __shared__ int hist[8][NN + 1];  // key 0..63 = valid (64-c): whales first; 64 = zero-fill
    __shared__ int offs[8][NN + 1];
    const int tid = (int)threadIdx.x;

    for (int x = tid; x < 8 * (NN + 1); x += 512)
        (&hist[0][0])[x] = 0;
    for (int b = tid; b < BATCH; b += 512) cLds[b] = counts[b];
    __syncthreads();

    for (int w = tid; w < NITEMS; w += 512) {
        const int b = w >> 3, ic = w & 7;
        const int c = cLds[b];
        const int key = (ic * ICHUNK < c) ? (NN - c) : NN;
        atomicAdd(&hist[b & 7][key], 1);
    }
    __syncthreads();

    if (tid < 8) {  // serial 65-entry exclusive scan per bucket
        int acc = 0;
        for (int k = 0; k <= NN; ++k) { offs[tid][k] = acc; acc += hist[tid][k]; }
    }
    __syncthreads();

    for (int w = tid; w < NITEMS; w += 512) {
        const int b = w >> 3, ic = w & 7;
        const int c = cLds[b];
        const int key = (ic * ICHUNK < c) ? (NN - c) : NN;
        const int pos = atomicAdd(&offs[b & 7][key], 1);  // rank within bucket
        items[pos * 8 + (b & 7)] = w;                     // slot%8 == b%8
    }
}

// ---------------- main body: K4 phase-split --------------------------------
__device__ __forceinline__ void mp_body(
    int b, int ic,
    const float* __restrict__ A, const float* __restrict__ B,
    const int* __restrict__ counts, float* __restrict__ out)
{
    const int i0 = ic << 3;
    const int c  = counts[b];
    const int tid = (int)threadIdx.x;
    const int d  = tid & 31;             // channel
    const int jg = tid >> 5;             // 0..15, group of 4 j's
    const int jb = jg << 2;              // j base

    const size_t base = (size_t)b * BSTRIDE;
    float* __restrict__ Ob = out + base + (size_t)i0 * RSTRIDE + (size_t)jb * ND + d;

    if (i0 >= c) {
        #pragma unroll
        for (int ii = 0; ii < ICHUNK; ++ii)
            #pragma unroll
            for (int jj = 0; jj < 4; ++jj)
                Ob[(size_t)ii * RSTRIDE + jj * ND] = 0.0f;
        return;
    }

    const float* __restrict__ Ai = A + base + (size_t)i0 * RSTRIDE + d;
    const float* __restrict__ Bb = B + base + (size_t)jb * ND + d;

    float acc[ICHUNK][4];
    #pragma unroll
    for (int ii = 0; ii < ICHUNK; ++ii)
        #pragma unroll
        for (int jj = 0; jj < 4; ++jj)
            acc[ii][jj] = 0.0f;

    const bool waveActive = (((tid >> 6) << 3) < c);

    if (waveActive) {
        const int c4 = c & ~3;
        int k = 0;
        #pragma unroll 1
        for (; k < c4; k += 4) {
            // ---- phase 1: issue ALL 48 loads (4 k-steps), no use in between
            float av[4][ICHUNK];
            float bv[4][4];
            #pragma unroll
            for (int kk = 0; kk < 4; ++kk) {
                #pragma unroll
                for (int ii = 0; ii < ICHUNK; ++ii)
                    av[kk][ii] = Ai[(size_t)ii * RSTRIDE + (size_t)(k + kk) * ND];
                #pragma unroll
                for (int jj = 0; jj < 4; ++jj)
                    bv[kk][jj] = Bb[(size_t)(k + kk) * RSTRIDE + jj * ND];
            }
            // ---- phase 2: 128 FMAs
            #pragma unroll
            for (int kk = 0; kk < 4; ++kk)
                #pragma unroll
                for (int ii = 0; ii < ICHUNK; ++ii)
                    #pragma unroll
                    for (int jj = 0; jj < 4; ++jj)
                        acc[ii][jj] = fmaf(av[kk][ii], bv[kk][jj], acc[ii][jj]);
        }
        // tail (<=3 iterations)
        #pragma unroll 1
        for (; k < c; ++k) {
            float av[ICHUNK];
            #pragma unroll
            for (int ii = 0; ii < ICHUNK; ++ii)
                av[ii] = Ai[(size_t)ii * RSTRIDE + (size_t)k * ND];
            float bv[4];
            #pragma unroll
            for (int jj = 0; jj < 4; ++jj)
                bv[jj] = Bb[(size_t)k * RSTRIDE + jj * ND];
            #pragma unroll
            for (int ii = 0; ii < ICHUNK; ++ii)
                #pragma unroll
                for (int jj = 0; jj < 4; ++jj)
                    acc[ii][jj] = fmaf(av[ii], bv[jj], acc[ii][jj]);
        }
    }

    #pragma unroll
    for (int ii = 0; ii < ICHUNK; ++ii) {
        const bool iv = (i0 + ii) < c;
        #pragma unroll
        for (int jj = 0; jj < 4; ++jj) {
            const bool v = iv && ((jb + jj) < c);
            Ob[(size_t)ii * RSTRIDE + jj * ND] = v ? acc[ii][jj] : 0.0f;
        }
    }
}

__global__ __launch_bounds__(512, 4) void mp_kernel_sorted(
    const float* __restrict__ A, const float* __restrict__ B,
    const int* __restrict__ counts, float* __restrict__ out,
    const int* __restrict__ items)
{
    const int w = items[blockIdx.x];
    mp_body(w >> 3, w & 7, A, B, counts, out);
}

__global__ __launch_bounds__(512, 4) void mp_kernel_direct(
    const float* __restrict__ A, const float* __restrict__ B,
    const int* __restrict__ counts, float* __restrict__ out)
{
    mp_body(blockIdx.x & (BATCH - 1), blockIdx.x >> 8, A, B, counts, out);
}

extern "C" void kernel_launch(void* const* d_in, const int* in_sizes, int n_in,
                              void* d_out, int out_size, void* d_ws, size_t ws_size,
                              hipStream_t stream)
{
    const float* A      = (const float*)d_in[0];
    const float* B      = (const float*)d_in[1];
    const int*   counts = (const int*)d_in[2];
    float* out = (float*)d_out;

    if (ws_size >= NITEMS * sizeof(int)) {
        int* items = (int*)d_ws;
        mp_prologue<<<dim3(1), dim3(512), 0, stream>>>(counts, items);
        mp_kernel_sorted<<<dim3(NITEMS), dim3(512), 0, stream>>>(A, B, counts, out, items);
    } else {
        mp_kernel_direct<<<dim3(NITEMS), dim3(512), 0, stream>>>(A, B, counts, out);
    }
}

// Round 10
// 78.862 us; speedup vs baseline: 1.4854x; 1.4854x over previous
//
#include <hip/hip_runtime.h>

// out[b,i,j,d] = sum_{k<c} A[b,i,k,d] * B[b,k,j,d]   for i,j < c, else 0
// A: (256,64,64,32) f32, strides: b:131072, i:2048, k:32, d:1
// B: (256,64,64,32) f32, strides: b:131072, k:2048, j:32, d:1
//
// v10: v9 (XCD-bucketed longest-first schedule + K4 phase-split body)
// + T19 sched_group_barrier pinning the K4 region to
//   [16 VALU addr][48 VMEM_READ][128 VALU FMA].
// Diagnosis: v4/v9 VGPR counts (44/52) prove LLVM sinks every load to its
// use (1 load in flight/wave, ~250cyc stall per load group). Group barriers
// force all 48 loads of a K4 step ahead of the FMA block; waitcnts become
// incremental, exposing ~1 latency per 4 k-iters instead of ~8-12.

#define BATCH 256
#define NN 64
#define ND 32
#define BSTRIDE (NN * NN * ND)   // 131072
#define RSTRIDE (NN * ND)        // 2048
#define ICHUNK 8
#define NITEMS (BATCH * (NN / ICHUNK))  // 2048, item w = b*8 + ic

// ---------------- prologue: per-XCD-bucket counting sort (v8, unchanged) ----
__global__ __launch_bounds__(512) void mp_prologue(
    const int* __restrict__ counts, int* __restrict__ items)
{
    __shared__ int cLds[BATCH];
    __shared__ int hist[8][NN + 1];  // key 0..63 = valid (64-c): whales first; 64 = zero-fill
    __shared__ int offs[8][NN + 1];
    const int tid = (int)threadIdx.x;

    for (int x = tid; x < 8 * (NN + 1); x += 512)
        (&hist[0][0])[x] = 0;
    for (int b = tid; b < BATCH; b += 512) cLds[b] = counts[b];
    __syncthreads();

    for (int w = tid; w < NITEMS; w += 512) {
        const int b = w >> 3, ic = w & 7;
        const int c = cLds[b];
        const int key = (ic * ICHUNK < c) ? (NN - c) : NN;
        atomicAdd(&hist[b & 7][key], 1);
    }
    __syncthreads();

    if (tid < 8) {  // serial 65-entry exclusive scan per bucket
        int acc = 0;
        for (int k = 0; k <= NN; ++k) { offs[tid][k] = acc; acc += hist[tid][k]; }
    }
    __syncthreads();

    for (int w = tid; w < NITEMS; w += 512) {
        const int b = w >> 3, ic = w & 7;
        const int c = cLds[b];
        const int key = (ic * ICHUNK < c) ? (NN - c) : NN;
        const int pos = atomicAdd(&offs[b & 7][key], 1);  // rank within bucket
        items[pos * 8 + (b & 7)] = w;                     // slot%8 == b%8
    }
}

// ---------------- main body: K4 phase-split + sched_group_barrier -----------
__device__ __forceinline__ void mp_body(
    int b, int ic,
    const float* __restrict__ A, const float* __restrict__ B,
    const int* __restrict__ counts, float* __restrict__ out)
{
    const int i0 = ic << 3;
    const int c  = counts[b];
    const int tid = (int)threadIdx.x;
    const int d  = tid & 31;             // channel
    const int jg = tid >> 5;             // 0..15, group of 4 j's
    const int jb = jg << 2;              // j base

    const size_t base = (size_t)b * BSTRIDE;
    float* __restrict__ Ob = out + base + (size_t)i0 * RSTRIDE + (size_t)jb * ND + d;

    if (i0 >= c) {
        #pragma unroll
        for (int ii = 0; ii < ICHUNK; ++ii)
            #pragma unroll
            for (int jj = 0; jj < 4; ++jj)
                Ob[(size_t)ii * RSTRIDE + jj * ND] = 0.0f;
        return;
    }

    const float* __restrict__ Ai = A + base + (size_t)i0 * RSTRIDE + d;
    const float* __restrict__ Bb = B + base + (size_t)jb * ND + d;

    float acc[ICHUNK][4];
    #pragma unroll
    for (int ii = 0; ii < ICHUNK; ++ii)
        #pragma unroll
        for (int jj = 0; jj < 4; ++jj)
            acc[ii][jj] = 0.0f;

    const bool waveActive = (((tid >> 6) << 3) < c);

    if (waveActive) {
        const int c4 = c & ~3;
        int k = 0;
        #pragma unroll 1
        for (; k < c4; k += 4) {
            // ---- phase 1: issue ALL 48 loads (4 k-steps)
            float av[4][ICHUNK];
            float bv[4][4];
            #pragma unroll
            for (int kk = 0; kk < 4; ++kk) {
                #pragma unroll
                for (int ii = 0; ii < ICHUNK; ++ii)
                    av[kk][ii] = Ai[(size_t)ii * RSTRIDE + (size_t)(k + kk) * ND];
                #pragma unroll
                for (int jj = 0; jj < 4; ++jj)
                    bv[kk][jj] = Bb[(size_t)(k + kk) * RSTRIDE + jj * ND];
            }
            // ---- phase 2: 128 FMAs
            #pragma unroll
            for (int kk = 0; kk < 4; ++kk)
                #pragma unroll
                for (int ii = 0; ii < ICHUNK; ++ii)
                    #pragma unroll
                    for (int jj = 0; jj < 4; ++jj)
                        acc[ii][jj] = fmaf(av[kk][ii], bv[kk][jj], acc[ii][jj]);

            // ---- T19: pin this region's schedule: addr VALU, then all 48
            // loads clustered, then the FMA block. Masks per LLVM
            // SchedGroupMask: VALU=0x2, VMEM_READ=0x20.
            __builtin_amdgcn_sched_group_barrier(0x002, 16, 0);
            __builtin_amdgcn_sched_group_barrier(0x020, 48, 0);
            __builtin_amdgcn_sched_group_barrier(0x002, 128, 0);
        }
        // tail (<=3 iterations)
        #pragma unroll 1
        for (; k < c; ++k) {
            float av[ICHUNK];
            #pragma unroll
            for (int ii = 0; ii < ICHUNK; ++ii)
                av[ii] = Ai[(size_t)ii * RSTRIDE + (size_t)k * ND];
            float bv[4];
            #pragma unroll
            for (int jj = 0; jj < 4; ++jj)
                bv[jj] = Bb[(size_t)k * RSTRIDE + jj * ND];
            #pragma unroll
            for (int ii = 0; ii < ICHUNK; ++ii)
                #pragma unroll
                for (int jj = 0; jj < 4; ++jj)
                    acc[ii][jj] = fmaf(av[ii], bv[jj], acc[ii][jj]);
        }
    }

    #pragma unroll
    for (int ii = 0; ii < ICHUNK; ++ii) {
        const bool iv = (i0 + ii) < c;
        #pragma unroll
        for (int jj = 0; jj < 4; ++jj) {
            const bool v = iv && ((jb + jj) < c);
            Ob[(size_t)ii * RSTRIDE + jj * ND] = v ? acc[ii][jj] : 0.0f;
        }
    }
}

__global__ __launch_bounds__(512, 4) void mp_kernel_sorted(
    const float* __restrict__ A, const float* __restrict__ B,
    const int* __restrict__ counts, float* __restrict__ out,
    const int* __restrict__ items)
{
    const int w = items[blockIdx.x];
    mp_body(w >> 3, w & 7, A, B, counts, out);
}

__global__ __launch_bounds__(512, 4) void mp_kernel_direct(
    const float* __restrict__ A, const float* __restrict__ B,
    const int* __restrict__ counts, float* __restrict__ out)
{
    mp_body(blockIdx.x & (BATCH - 1), blockIdx.x >> 8, A, B, counts, out);
}

extern "C" void kernel_launch(void* const* d_in, const int* in_sizes, int n_in,
                              void* d_out, int out_size, void* d_ws, size_t ws_size,
                              hipStream_t stream)
{
    const float* A      = (const float*)d_in[0];
    const float* B      = (const float*)d_in[1];
    const int*   counts = (const int*)d_in[2];
    float* out = (float*)d_out;

    if (ws_size >= NITEMS * sizeof(int)) {
        int* items = (int*)d_ws;
        mp_prologue<<<dim3(1), dim3(512), 0, stream>>>(counts, items);
        mp_kernel_sorted<<<dim3(NITEMS), dim3(512), 0, stream>>>(A, B, counts, out, items);
    } else {
        mp_kernel_direct<<<dim3(NITEMS), dim3(512), 0, stream>>>(A, B, counts, out);
    }
}